// Round 2
// baseline (65.137 us; speedup 1.0000x reference)
//
#include <hip/hip_runtime.h>

// Banded-block sparse attention, B=4, S=4096, D=128, block=64, w=32.
// Masked scores are 0 (not -inf) -> closed-form out-of-band correction.
// fp16 MFMA path, exp2 domain, swapped QK^T, defer-max (THR=8 log2 units).
//
// R2: 32 q-rows per wave (wg covers q-block PAIR ib=2p,2p+1; 4 waves x 256thr).
// Each kf/vbf LDS fragment feeds 2 MFMAs -> LDS bytes/cell 144->80 KB (was the
// binding pipe at ~71%). LDS 48KB (K16+V16+P16) -> 3 wg/CU. CHUNKS=8 over the
// union band (grid 1024 = 3 resident/CU + 256 backfill for tail balance).
// Waves skip <=1 out-of-band edge tile via wave-uniform predicate.

typedef _Float16 f16;
typedef __attribute__((ext_vector_type(8))) _Float16 f16x8;
typedef __attribute__((ext_vector_type(4))) _Float16 f16x4;
typedef __attribute__((ext_vector_type(4))) float f32x4;

#define MFMA16(a, b, c) __builtin_amdgcn_mfma_f32_16x16x32_f16((a), (b), (c), 0, 0, 0)

#define BATCH 4
#define SEQ   4096
#define DIM   128
#define NB    64
#define WBAND 32
#define LOG2E 1.44269504088896f
#define DTHR  8.0f

#define KTILE 16384   // 64 rows x 128 f16, 256B rows, chunk XOR-swizzled
#define VTILE 16384   // 128 d-rows x 64 f16, 128B rows, chunk XOR-swizzled
#define TSTR  72

#define CHUNKS 8
#define PART_STRIDE 16896  // 16 KB o (f16, [2 qh][8 slot][64 lane][16B]) + 512B (m,l)

__device__ __forceinline__ void gl16(const char* g, char* l) {
  __builtin_amdgcn_global_load_lds(
      (const __attribute__((address_space(1))) void*)g,
      (__attribute__((address_space(3))) void*)l, 16, 0, 0);
}

// ---------------------------------------------------------------------------
__global__ __launch_bounds__(256) void convert_kernel(
    const float* __restrict__ K, const float* __restrict__ V,
    f16* __restrict__ KT, f16* __restrict__ VT, float* __restrict__ BS) {
  __shared__ f16 T[128 * TSTR];
  const int blk = blockIdx.x;
  const int b = blk >> 6, jb = blk & 63;
  const int s0 = jb * 64;
  const int t = threadIdx.x;
  char* ktile = (char*)KT + (size_t)blk * KTILE;
  char* vtile = (char*)VT + (size_t)blk * VTILE;

#pragma unroll
  for (int i = 0; i < 4; ++i) {
    int idx = t + i * 256;
    int row = idx >> 4;
    int c = idx & 15;
    const float* src = K + ((size_t)(b * SEQ + s0 + row)) * DIM + c * 8;
    float4 a = *(const float4*)src;
    float4 d = *(const float4*)(src + 4);
    f16x8 h = {(f16)a.x, (f16)a.y, (f16)a.z, (f16)a.w,
               (f16)d.x, (f16)d.y, (f16)d.z, (f16)d.w};
    *(f16x8*)(ktile + row * 256 + ((c ^ (row & 15)) * 16)) = h;
  }

#pragma unroll
  for (int i = 0; i < 8; ++i) {
    int idx = t + i * 256;
    int row = idx >> 5;
    int c4 = (idx & 31) * 4;
    float4 v = *(const float4*)(V + (size_t)(b * SEQ + s0 + row) * DIM + c4);
    T[(c4 + 0) * TSTR + row] = (f16)v.x;
    T[(c4 + 1) * TSTR + row] = (f16)v.y;
    T[(c4 + 2) * TSTR + row] = (f16)v.z;
    T[(c4 + 3) * TSTR + row] = (f16)v.w;
  }
  __syncthreads();

#pragma unroll
  for (int i = 0; i < 4; ++i) {
    int idx = t + i * 256;
    int d = idx >> 3;
    int c = idx & 7;
    f16x8 val = *(const f16x8*)(T + d * TSTR + c * 8);
    *(f16x8*)(vtile + d * 128 + ((c ^ (d & 7)) * 16)) = val;
  }

  if (t < 128) {
    float s = 0.f;
    for (int k = 0; k < 64; ++k) s += (float)T[t * TSTR + k];
    BS[(b * NB + jb) * DIM + t] = s;
  }
}

// ---------------------------------------------------------------------------
// 49152 B LDS: K tile @0 (16K), V tile @16384 (16K), P @32768 (4 waves x 4K)
__global__ __launch_bounds__(256, 3) void attn_kernel(
    const float* __restrict__ Q, const f16* __restrict__ KT,
    const f16* __restrict__ VT, char* __restrict__ PART) {
  __shared__ __align__(16) char smem[49152];

  const int id = blockIdx.x;
  const int lin = (id & 7) * 128 + (id >> 3);  // XCD-contiguous pair bands
  const int ck = lin & 7;
  const int pair = lin >> 3;   // 0..127
  const int b = pair >> 5, p = pair & 31;

  const int t = threadIdx.x;
  const int w = t >> 6, l = t & 63, lg = l >> 4, ll = l & 15;
  const int half = w >> 1, qh = w & 1;   // wave -> (block-in-pair, q-half)
  const int myib = p * 2 + half;

  const int jloU = max(0, p * 2 - WBAND);
  const int jhiU = min(NB, p * 2 + 1 + WBAND);
  const int lenU = jhiU - jloU;            // 33..64
  const int c = (lenU + CHUNKS - 1) >> 3;  // 5..8
  const int j0 = jloU + ck * c;
  const int nloc = min(c, jhiU - j0);      // may be <= 0 -> zero partial
  const int mylo = max(0, myib - WBAND);
  const int myhi = min(NB, myib + WBAND);

  // Q fragments for 2 quadrants (pre-scaled by log2 e). B operand layout:
  // col = ll = q row (within quadrant), k = lg*8+e.
  f16x8 qf[2][4];
#pragma unroll
  for (int s = 0; s < 2; ++s) {
    const float* qrow =
        Q + ((size_t)(b * SEQ + myib * 64 + qh * 32 + s * 16 + ll)) * DIM;
#pragma unroll
    for (int ks = 0; ks < 4; ++ks) {
      int d0 = ks * 32 + lg * 8;
      float4 a = *(const float4*)(qrow + d0);
      float4 cc = *(const float4*)(qrow + d0 + 4);
      float vv[8] = {a.x, a.y, a.z, a.w, cc.x, cc.y, cc.z, cc.w};
#pragma unroll
      for (int e = 0; e < 8; ++e) qf[s][ks][e] = (f16)(vv[e] * LOG2E);
    }
  }

  float m2[2] = {0.f, 0.f};   // running max (log2 domain); 0 = masked baseline
  float ell[2] = {0.f, 0.f};  // per-lane partial row sums
  f32x4 o[2][8];
#pragma unroll
  for (int s = 0; s < 2; ++s)
#pragma unroll
    for (int nt = 0; nt < 8; ++nt) o[s][nt] = (f32x4){0.f, 0.f, 0.f, 0.f};

  f16* Pw = (f16*)(smem + 32768 + w * 4096);  // 2 quadrants x 16 rows x 64 f16
  const char* kb = smem;
  const char* vb = smem + 16384;

  auto stage = [&](int jb) {
    const char* kg = (const char*)KT + ((size_t)(b * NB + jb)) * KTILE + t * 16;
    const char* vg = (const char*)VT + ((size_t)(b * NB + jb)) * VTILE + t * 16;
#pragma unroll
    for (int i = 0; i < 4; ++i) gl16(kg + i * 4096, smem + t * 16 + i * 4096);
#pragma unroll
    for (int i = 0; i < 4; ++i) gl16(vg + i * 4096, smem + 16384 + t * 16 + i * 4096);
  };

  if (nloc > 0) {
    stage(j0);
    __syncthreads();

    for (int tt = 0; tt < nloc; ++tt) {
      const int j = j0 + tt;
      const bool act = (j >= mylo) && (j < myhi);  // wave-uniform
      if (act) {
        // S^T = K * Q^T for both quadrants; kf read once, 2 MFMAs.
        f32x4 sacc[2][4];
#pragma unroll
        for (int s = 0; s < 2; ++s)
#pragma unroll
          for (int jt = 0; jt < 4; ++jt) sacc[s][jt] = (f32x4){0.f, 0.f, 0.f, 0.f};
        __builtin_amdgcn_s_setprio(1);
#pragma unroll
        for (int ks = 0; ks < 4; ++ks) {
#pragma unroll
          for (int jt = 0; jt < 4; ++jt) {
            int row = jt * 16 + ll;
            f16x8 kf = *(const f16x8*)(kb + row * 256 + (((ks * 4 + lg) ^ ll) * 16));
            sacc[0][jt] = MFMA16(kf, qf[0][ks], sacc[0][jt]);
            sacc[1][jt] = MFMA16(kf, qf[1][ks], sacc[1][jt]);
          }
        }
        __builtin_amdgcn_s_setprio(0);

#pragma unroll
        for (int s = 0; s < 2; ++s) {
          // lane-local row max (16 values) + 2 cross-lane combines
          float vm = sacc[s][0][0];
#pragma unroll
          for (int jt = 0; jt < 4; ++jt)
#pragma unroll
            for (int r = 0; r < 4; ++r) vm = fmaxf(vm, sacc[s][jt][r]);
          vm = fmaxf(vm, __shfl_xor(vm, 16));
          vm = fmaxf(vm, __shfl_xor(vm, 32));

          if (__any(vm - m2[s] > DTHR)) {
            float nm = fmaxf(m2[s], vm);
            float scl = __builtin_amdgcn_exp2f(m2[s] - nm);
            m2[s] = nm;
            ell[s] *= scl;
            float sb[4];
#pragma unroll
            for (int r = 0; r < 4; ++r) sb[r] = __shfl(scl, lg * 4 + r);
#pragma unroll
            for (int nt = 0; nt < 8; ++nt)
#pragma unroll
              for (int r = 0; r < 4; ++r) o[s][nt][r] *= sb[r];
          }

          // P = 2^(S - m2); pack 4 keys -> one ds_write_b64, XOR-swizzled row
          float rsum = 0.f;
#pragma unroll
          for (int jt = 0; jt < 4; ++jt) {
            f16x4 pk;
#pragma unroll
            for (int r = 0; r < 4; ++r) {
              float pv = __builtin_amdgcn_exp2f(sacc[s][jt][r] - m2[s]);
              rsum += pv;
              pk[r] = (f16)pv;
            }
            *(f16x4*)(Pw + s * 1024 + ll * 64 +
                      ((jt * 16 + lg * 4) ^ ((ll & 7) << 3))) = pk;
          }
          ell[s] += rsum;
        }

        // PV: vbf read once, 2 MFMAs (one per quadrant)
        __builtin_amdgcn_s_setprio(1);
#pragma unroll
        for (int ks2 = 0; ks2 < 2; ++ks2) {
          int pcol = (ks2 * 32 + lg * 8) ^ ((ll & 7) << 3);
          f16x8 pa0 = *(const f16x8*)(Pw + ll * 64 + pcol);
          f16x8 pa1 = *(const f16x8*)(Pw + 1024 + ll * 64 + pcol);
#pragma unroll
          for (int nt = 0; nt < 8; ++nt) {
            int d = nt * 16 + ll;
            f16x8 vbf = *(const f16x8*)(vb + d * 128 + (((ks2 * 4 + lg) ^ (ll & 7)) * 16));
            o[0][nt] = MFMA16(pa0, vbf, o[0][nt]);
            o[1][nt] = MFMA16(pa1, vbf, o[1][nt]);
          }
        }
        __builtin_amdgcn_s_setprio(0);
      }
      __syncthreads();                        // all waves done reading K/V
      if (tt + 1 < nloc) stage(j0 + tt + 1);  // refill single buffer
      __syncthreads();                        // vmcnt(0) drain -> tile ready
    }
  }

  // finalize per-row sums across lg lanes
#pragma unroll
  for (int s = 0; s < 2; ++s) {
    ell[s] += __shfl_xor(ell[s], 16);
    ell[s] += __shfl_xor(ell[s], 32);
  }

  // partial store, fully coalesced 16B/lane: [qh][slot=s*4+g][lane][16B]
  char* pb = PART + ((size_t)((pair * CHUNKS + ck) * 2 + half)) * PART_STRIDE;
#pragma unroll
  for (int s = 0; s < 2; ++s)
#pragma unroll
    for (int g = 0; g < 4; ++g) {
      f16x8 hh;
#pragma unroll
      for (int r = 0; r < 4; ++r) {
        hh[r] = (f16)o[s][2 * g][r];
        hh[4 + r] = (f16)o[s][2 * g + 1][r];
      }
      *(f16x8*)(pb + qh * 8192 + ((s * 4 + g) * 64 + l) * 16) = hh;
    }
  if (lg == 0) {
#pragma unroll
    for (int s = 0; s < 2; ++s)
      *(float2*)(pb + 16384 + (qh * 32 + s * 16 + ll) * 8) =
          make_float2(m2[s], ell[s]);
  }
}

// ---------------------------------------------------------------------------
// Flash-merge of 8 chunk partials + closed-form out-of-band correction.
__global__ __launch_bounds__(256) void merge_kernel(
    const char* __restrict__ PART, const float* __restrict__ BS,
    float* __restrict__ Out) {
  __shared__ float VoutS[DIM];
  __shared__ float mlS[CHUNKS][64][2];

  const int id = blockIdx.x;
  const int lin = (id & 7) * 32 + (id >> 3);  // match attn pair->XCD mapping
  const int pair = lin >> 1, half = lin & 1;
  const int b = pair >> 5;
  const int ib = (pair & 31) * 2 + half;
  const int t = threadIdx.x;
  const int l = t & 63, lg = (t >> 4) & 3, ll = t & 15;
  const int sub = (t >> 6) & 1, qh = t >> 7;

  const int jlo = max(0, ib - WBAND);
  const int jhi = min(NB, ib + WBAND);
  const float cnt_out = (float)(SEQ - (jhi - jlo) * 64);

  if (t < DIM) {
    float s = 0.f;
    for (int j = 0; j < jlo; ++j) s += BS[(b * NB + j) * DIM + t];
    for (int j = jhi; j < NB; ++j) s += BS[(b * NB + j) * DIM + t];
    VoutS[t] = s;
  }

  const size_t pb0 = ((size_t)(pair * CHUNKS * 2 + half)) * PART_STRIDE;
  // chunk k lives at PART + pb0 + k*2*PART_STRIDE
  for (int i = t; i < CHUNKS * 64; i += 256) {
    int k = i >> 6, row = i & 63;
    *(float2*)&mlS[k][row][0] = *(const float2*)(
        PART + pb0 + (size_t)k * 2 * PART_STRIDE + 16384 + row * 8);
  }
  __syncthreads();

  float aw[4][CHUNKS], en[4], inv[4];
#pragma unroll
  for (int r = 0; r < 4; ++r) {
    int row = qh * 32 + sub * 16 + lg * 4 + r;
    float M = mlS[0][row][0];
#pragma unroll
    for (int k = 1; k < CHUNKS; ++k) M = fmaxf(M, mlS[k][row][0]);
    en[r] = __builtin_amdgcn_exp2f(-M);
    float den = cnt_out * en[r];
#pragma unroll
    for (int k = 0; k < CHUNKS; ++k) {
      aw[r][k] = __builtin_amdgcn_exp2f(mlS[k][row][0] - M);
      den += aw[r][k] * mlS[k][row][1];
    }
    inv[r] = 1.f / den;
  }

  float acc[8][4];
#pragma unroll
  for (int nt = 0; nt < 8; ++nt)
#pragma unroll
    for (int r = 0; r < 4; ++r) acc[nt][r] = 0.f;

  for (int k = 0; k < CHUNKS; ++k) {
    const char* oc = PART + pb0 + (size_t)k * 2 * PART_STRIDE + qh * 8192;
#pragma unroll
    for (int g = 0; g < 4; ++g) {
      f16x8 h = *(const f16x8*)(oc + ((sub * 4 + g) * 64 + l) * 16);
#pragma unroll
      for (int r = 0; r < 4; ++r) {
        acc[2 * g][r] += aw[r][k] * (float)h[r];
        acc[2 * g + 1][r] += aw[r][k] * (float)h[4 + r];
      }
    }
  }

  const int q0 = ib * 64;
#pragma unroll
  for (int nt = 0; nt < 8; ++nt) {
    int col = nt * 16 + ll;
    float vout = VoutS[col];
#pragma unroll
    for (int r = 0; r < 4; ++r) {
      int row = qh * 32 + sub * 16 + lg * 4 + r;
      Out[((size_t)(b * SEQ + q0 + row)) * DIM + col] =
          (acc[nt][r] + en[r] * vout) * inv[r];
    }
  }
}

// ---------------------------------------------------------------------------
extern "C" void kernel_launch(void* const* d_in, const int* in_sizes, int n_in,
                              void* d_out, int out_size, void* d_ws, size_t ws_size,
                              hipStream_t stream) {
  const float* Q = (const float*)d_in[0];
  const float* K = (const float*)d_in[1];
  const float* V = (const float*)d_in[2];
  float* Out = (float*)d_out;

  char* ws = (char*)d_ws;
  f16* KTg = (f16*)ws;                                 // 4 MB
  f16* VTg = (f16*)(ws + (size_t)BATCH * NB * KTILE);  // +4 MB
  float* BS = (float*)(ws + 2 * (size_t)BATCH * NB * KTILE);  // +128 KB
  char* PART = ws + 2 * (size_t)BATCH * NB * KTILE + (size_t)BATCH * NB * DIM * 4;  // 34.6 MB

  convert_kernel<<<dim3(BATCH * NB), 256, 0, stream>>>(K, V, KTg, VTg, BS);
  attn_kernel<<<dim3(BATCH * NB / 2 * CHUNKS), 256, 0, stream>>>(Q, KTg, VTg, PART);
  merge_kernel<<<dim3(BATCH * NB), 256, 0, stream>>>(PART, BS, Out);
}